// Round 19
// baseline (41.104 us; speedup 1.0000x reference)
//
#include <hip/hip_runtime.h>
#include <hip/hip_bf16.h>

#define N 1024
#define D 128
#define LEAK 0.2f

#define MROWS 2          // i-rows per mega block

// workspace layout (float offsets)
#define OFF_WPD  0
#define OFF_WUT  128
#define OFF_S1   256
#define OFF_S2   1280
#define OFF_BASE 2304

// ---------------------------------------------------------------------------
// K_A: prep + base (R14/R17 known-good, minus the W2t branch).
//   b 0..511 : rows 2b, 2b+1:  Wh = h@W^T, s1/s2 = Wh@a, base = Wh@W1h^T + b1
//   b 512    : wpd/wut extraction
__global__ __launch_bounds__(256) void prep_base_kernel(
    const float* __restrict__ W, const float* __restrict__ W1,
    const float* __restrict__ a,
    const float* __restrict__ h, const float* __restrict__ b1,
    float* __restrict__ wpd, float* __restrict__ wut,
    float* __restrict__ s1, float* __restrict__ s2, float* __restrict__ base) {
    __shared__ float pool[512];
    __shared__ float red[4], red2[4];
    int b = blockIdx.x, tid = threadIdx.x;
    if (b < 512) {
        float* hl  = pool;          // [2][128]
        float* whl = pool + 256;    // [2][128]
        int i0 = b * 2;
        if (tid < 64) ((float4*)hl)[tid] = ((const float4*)(h + i0 * D))[tid];
        __syncthreads();
        int r = tid >> 7, l = tid & 127;
        float u = 0.f;
        #pragma unroll 8
        for (int q = 0; q < D; q += 4) {
            float4 hq = *(const float4*)&hl[r * D + q];
            float4 wq = *(const float4*)&W[l * D + q];
            u = fmaf(hq.x, wq.x, u); u = fmaf(hq.y, wq.y, u);
            u = fmaf(hq.z, wq.z, u); u = fmaf(hq.w, wq.w, u);
        }
        whl[r * D + l] = u;
        __syncthreads();
        {
            int w = tid >> 6, l63 = tid & 63;
            int row = w >> 1, half = w & 1;
            float wh = whl[row * D + half * 64 + l63];
            float p1 = wh * a[half * 64 + l63];
            float p2 = wh * a[D + half * 64 + l63];
            #pragma unroll
            for (int off = 32; off > 0; off >>= 1) {
                p1 += __shfl_xor(p1, off);
                p2 += __shfl_xor(p2, off);
            }
            if (l63 == 0) { red[w] = p1; red2[w] = p2; }
        }
        __syncthreads();
        if (tid < 2) {
            s1[i0 + tid] = red[2 * tid] + red[2 * tid + 1];
            s2[i0 + tid] = red2[2 * tid] + red2[2 * tid + 1];
        }
        float acc = b1[l];
        #pragma unroll 8
        for (int q = 0; q < D; q += 2) {
            float2 wh2 = *(const float2*)&whl[r * D + q];
            float2 x = *(const float2*)&W1[l * (D + 2) + q];
            acc = fmaf(wh2.x, x.x, acc);
            acc = fmaf(wh2.y, x.y, acc);
        }
        base[(i0 + r) * D + l] = acc;
    } else {
        if (tid < 128) wpd[tid] = W1[tid * (D + 2) + D];
        else           wut[tid - 128] = W1[(tid - 128) * (D + 2) + D + 1];
    }
}

// ---------------------------------------------------------------------------
// K_B: mega v10 (R17 best-known, 40.0us) with W2 read directly in epilogue.
//   512 blocks x 1024 thr, MROWS=2, 8 waves/SIMD. LDS 41KB -> 2 blocks/CU.
//   Main loop: 2x base b128 (L2) + scalar LDS broadcasts; no barriers.
__global__ __launch_bounds__(1024, 8) void mega_kernel(
    const float* __restrict__ base, const float* __restrict__ s1,
    const float* __restrict__ s2, const int* __restrict__ adj,
    const float* __restrict__ pd, const float* __restrict__ ut,
    const float* __restrict__ wpd, const float* __restrict__ wut,
    const float* __restrict__ W2, const float* __restrict__ b2,
    float* __restrict__ out) {
    __shared__ float al[MROWS][N];         // 8KB alpha
    __shared__ float pdl[MROWS][N];        // 8KB staged pd rows
    __shared__ float utl[MROWS][N];        // 8KB staged ut rows
    __shared__ float racc[16][MROWS][D];   // 16KB wave partials
    __shared__ float red[16], red2[16], gsum[MROWS];
    __shared__ float tl[MROWS][D];         // 1KB

    const int tid = threadIdx.x;           // 0..1023
    const int i0 = blockIdx.x * MROWS;
    const float* pdb = pd + (size_t)i0 * N;
    const float* utb = ut + (size_t)i0 * N;

    // ---- stage pd/ut rows into LDS (coalesced float4); alpha's final
    //      barrier makes them visible before the main loop ----
    {
        int half = tid >> 9, idx = tid & 511;    // 512 float4 = 2 rows x 1024
        const float* src = half ? utb : pdb;
        float* dst = half ? &utl[0][0] : &pdl[0][0];
        ((float4*)dst)[idx] = ((const float4*)src)[idx];
    }

    // ---- phase 0: alpha (row r <-> 512 threads = waves 8r..8r+7) ----
    {
        int r = tid >> 9;
        int i = i0 + r;
        int jb = (tid & 511) * 2;
        float s1i = s1[i];
        float2 sa = *(const float2*)&s2[jb];
        int2 ma = *(const int2*)&adj[i * N + jb];
        float e[2]; int mm[2];
        e[0] = s1i + sa.x; e[1] = s1i + sa.y;
        mm[0] = ma.x; mm[1] = ma.y;
        float mx = -3e38f;
        #pragma unroll
        for (int q = 0; q < 2; q++) {
            e[q] = e[q] > 0.f ? e[q] : LEAK * e[q];
            if (mm[q] > 0) mx = fmaxf(mx, e[q]);
        }
        #pragma unroll
        for (int off = 32; off > 0; off >>= 1) mx = fmaxf(mx, __shfl_xor(mx, off));
        int wid = tid >> 6, lane = tid & 63;
        if (lane == 0) red[wid] = mx;
        __syncthreads();
        {
            float m0 = fmaxf(fmaxf(red[8 * r], red[8 * r + 1]),
                             fmaxf(red[8 * r + 2], red[8 * r + 3]));
            float m1 = fmaxf(fmaxf(red[8 * r + 4], red[8 * r + 5]),
                             fmaxf(red[8 * r + 6], red[8 * r + 7]));
            mx = fmaxf(m0, m1);
        }
        float ev[2]; float sum = 0.f;
        #pragma unroll
        for (int q = 0; q < 2; q++) {
            ev[q] = (mm[q] > 0) ? __expf(e[q] - mx) : 0.f;
            sum += ev[q];
        }
        #pragma unroll
        for (int off = 32; off > 0; off >>= 1) sum += __shfl_xor(sum, off);
        if (lane == 0) red2[wid] = sum;
        __syncthreads();
        sum = red2[8 * r] + red2[8 * r + 1] + red2[8 * r + 2] + red2[8 * r + 3]
            + red2[8 * r + 4] + red2[8 * r + 5] + red2[8 * r + 6] + red2[8 * r + 7];
        float inv = sum > 0.f ? 1.f / sum : 0.f;
        *(float2*)&al[r][jb] = make_float2(ev[0] * inv, ev[1] * inv);
        if ((tid & 511) == 0) gsum[r] = sum;
    }
    __syncthreads();   // al + gsum + pdl/utl visible; no barriers until epilogue

    const int l16 = tid & 15, g = tid >> 4;        // 64 groups x 16 lanes
    const int k0a = l16 * 4, k0b = 64 + l16 * 4;
    const float4 wp0 = *(const float4*)&wpd[k0a];
    const float4 wp1 = *(const float4*)&wpd[k0b];
    const float4 wu0 = *(const float4*)&wut[k0a];
    const float4 wu1 = *(const float4*)&wut[k0b];

    float4 a0[MROWS] = {}, a1[MROWS] = {};

    #pragma unroll 2
    for (int c = 0; c < 16; c++) {
        int j = c * 64 + g;
        float4 b0  = *(const float4*)&base[j * D + k0a];
        float4 b1v = *(const float4*)&base[j * D + k0b];
        #pragma unroll
        for (int r = 0; r < MROWS; r++) {
            float spd = pdl[r][j];
            float sut = utl[r][j];
            float sal = al[r][j];
            float v;
            v = fmaxf(fmaf(spd, wp0.x, fmaf(sut, wu0.x, b0.x)), 0.f);  a0[r].x = fmaf(sal, v, a0[r].x);
            v = fmaxf(fmaf(spd, wp0.y, fmaf(sut, wu0.y, b0.y)), 0.f);  a0[r].y = fmaf(sal, v, a0[r].y);
            v = fmaxf(fmaf(spd, wp0.z, fmaf(sut, wu0.z, b0.z)), 0.f);  a0[r].z = fmaf(sal, v, a0[r].z);
            v = fmaxf(fmaf(spd, wp0.w, fmaf(sut, wu0.w, b0.w)), 0.f);  a0[r].w = fmaf(sal, v, a0[r].w);
            v = fmaxf(fmaf(spd, wp1.x, fmaf(sut, wu1.x, b1v.x)), 0.f); a1[r].x = fmaf(sal, v, a1[r].x);
            v = fmaxf(fmaf(spd, wp1.y, fmaf(sut, wu1.y, b1v.y)), 0.f); a1[r].y = fmaf(sal, v, a1[r].y);
            v = fmaxf(fmaf(spd, wp1.z, fmaf(sut, wu1.z, b1v.z)), 0.f); a1[r].z = fmaf(sal, v, a1[r].z);
            v = fmaxf(fmaf(spd, wp1.w, fmaf(sut, wu1.w, b1v.w)), 0.f); a1[r].w = fmaf(sal, v, a1[r].w);
        }
    }

    // ---- in-wave cross-group reduce: lanes l, l^16, l^32, l^48 share l16 ----
    #pragma unroll
    for (int r = 0; r < MROWS; r++) {
        #pragma unroll
        for (int m = 16; m <= 32; m <<= 1) {
            a0[r].x += __shfl_xor(a0[r].x, m); a0[r].y += __shfl_xor(a0[r].y, m);
            a0[r].z += __shfl_xor(a0[r].z, m); a0[r].w += __shfl_xor(a0[r].w, m);
            a1[r].x += __shfl_xor(a1[r].x, m); a1[r].y += __shfl_xor(a1[r].y, m);
            a1[r].z += __shfl_xor(a1[r].z, m); a1[r].w += __shfl_xor(a1[r].w, m);
        }
    }
    {
        int w = tid >> 6, lane = tid & 63;
        if (lane < 16) {
            #pragma unroll
            for (int r = 0; r < MROWS; r++) {
                *(float4*)&racc[w][r][k0a] = a0[r];
                *(float4*)&racc[w][r][k0b] = a1[r];
            }
        }
    }
    __syncthreads();
    if (tid < 256) {
        int rr = tid >> 7, k = tid & 127;
        float v = 0.f;
        #pragma unroll
        for (int w = 0; w < 16; w++) v += racc[w][rr][k];
        tl[rr][k] = v;
    }
    __syncthreads();
    // ---- final GEMM: out[i][d] = sum_k t[k] * W2[d][k] + gate*b2[d] ----
    if (tid < 256) {
        int rr = tid >> 7, d = tid & 127;
        float acc = (gsum[rr] > 0.f) ? b2[d] : 0.f;
        const float* w2row = W2 + d * D;       // W2[d][k] == W2t[k][d]
        #pragma unroll 8
        for (int k = 0; k < D; k++)
            acc = fmaf(tl[rr][k], w2row[k], acc);
        out[(i0 + rr) * D + d] = acc;
    }
}

// ---------------------------------------------------------------------------
extern "C" void kernel_launch(void* const* d_in, const int* in_sizes, int n_in,
                              void* d_out, int out_size, void* d_ws, size_t ws_size,
                              hipStream_t stream) {
    (void)in_sizes; (void)n_in; (void)out_size; (void)ws_size;
    const float* h   = (const float*)d_in[0];
    const int*   adj = (const int*)d_in[1];
    const float* pd  = (const float*)d_in[2];
    const float* ut  = (const float*)d_in[3];
    const float* W   = (const float*)d_in[4];
    const float* a   = (const float*)d_in[5];
    const float* W1  = (const float*)d_in[6];
    const float* b1  = (const float*)d_in[7];
    const float* W2  = (const float*)d_in[8];
    const float* b2  = (const float*)d_in[9];
    float* out = (float*)d_out;
    float* ws = (float*)d_ws;

    float* wpd   = ws + OFF_WPD;
    float* wut   = ws + OFF_WUT;
    float* s1    = ws + OFF_S1;
    float* s2    = ws + OFF_S2;
    float* baseb = ws + OFF_BASE;

    prep_base_kernel<<<513, 256, 0, stream>>>(W, W1, a, h, b1,
                                              wpd, wut, s1, s2, baseb);
    mega_kernel<<<N / MROWS, 1024, 0, stream>>>(baseb, s1, s2, adj, pd, ut,
                                                wpd, wut, W2, b2, out);
}

// Round 20
// 37.261 us; speedup vs baseline: 1.1031x; 1.1031x over previous
//
#include <hip/hip_runtime.h>
#include <hip/hip_bf16.h>

#define N 1024
#define D 128
#define LEAK 0.2f

#define MROWS 2          // i-rows per mega block

// workspace layout (float offsets)
#define OFF_W2T  0
#define OFF_WPD  16384
#define OFF_WUT  16512
#define OFF_S1   16640
#define OFF_S2   17664
#define OFF_BASE 18688

// ---------------------------------------------------------------------------
// K_A: prep + base, v3 (byte-identical to rounds 14/17 — known-good).
__global__ __launch_bounds__(256) void prep_base_kernel(
    const float* __restrict__ W, const float* __restrict__ W1,
    const float* __restrict__ W2, const float* __restrict__ a,
    const float* __restrict__ h, const float* __restrict__ b1,
    float* __restrict__ W2t, float* __restrict__ wpd, float* __restrict__ wut,
    float* __restrict__ s1, float* __restrict__ s2, float* __restrict__ base) {
    __shared__ float pool[4160];
    __shared__ float red[4], red2[4];
    int b = blockIdx.x, tid = threadIdx.x;
    if (b < 512) {
        float* hl  = pool;          // [2][128]
        float* whl = pool + 256;    // [2][128]
        int i0 = b * 2;
        if (tid < 64) ((float4*)hl)[tid] = ((const float4*)(h + i0 * D))[tid];
        __syncthreads();
        int r = tid >> 7, l = tid & 127;
        float u = 0.f;
        #pragma unroll 8
        for (int q = 0; q < D; q += 4) {
            float4 hq = *(const float4*)&hl[r * D + q];
            float4 wq = *(const float4*)&W[l * D + q];
            u = fmaf(hq.x, wq.x, u); u = fmaf(hq.y, wq.y, u);
            u = fmaf(hq.z, wq.z, u); u = fmaf(hq.w, wq.w, u);
        }
        whl[r * D + l] = u;
        __syncthreads();
        {
            int w = tid >> 6, l63 = tid & 63;
            int row = w >> 1, half = w & 1;
            float wh = whl[row * D + half * 64 + l63];
            float p1 = wh * a[half * 64 + l63];
            float p2 = wh * a[D + half * 64 + l63];
            #pragma unroll
            for (int off = 32; off > 0; off >>= 1) {
                p1 += __shfl_xor(p1, off);
                p2 += __shfl_xor(p2, off);
            }
            if (l63 == 0) { red[w] = p1; red2[w] = p2; }
        }
        __syncthreads();
        if (tid < 2) {
            s1[i0 + tid] = red[2 * tid] + red[2 * tid + 1];
            s2[i0 + tid] = red2[2 * tid] + red2[2 * tid + 1];
        }
        float acc = b1[l];
        #pragma unroll 8
        for (int q = 0; q < D; q += 2) {
            float2 wh2 = *(const float2*)&whl[r * D + q];
            float2 x = *(const float2*)&W1[l * (D + 2) + q];
            acc = fmaf(wh2.x, x.x, acc);
            acc = fmaf(wh2.y, x.y, acc);
        }
        base[(i0 + r) * D + l] = acc;
    } else if (b < 516) {
        int kbase = 32 * (b - 512);
        #pragma unroll
        for (int p = 0; p < 16; p++) {
            int idx = tid + p * 256;
            int rd = idx >> 5, cc = idx & 31;
            pool[cc * 129 + rd] = W2[rd * D + kbase + cc];
        }
        __syncthreads();
        #pragma unroll
        for (int p = 0; p < 16; p++) {
            int idx = tid + p * 256;
            int kl = idx >> 7, dd = idx & 127;
            W2t[(kbase + kl) * D + dd] = pool[kl * 129 + dd];
        }
    } else {
        if (tid < 128) wpd[tid] = W1[tid * (D + 2) + D];
        else           wut[tid - 128] = W1[(tid - 128) * (D + 2) + D + 1];
    }
}

// ---------------------------------------------------------------------------
// K_B: mega v13 = v10 (R17 best-known) + active-j compaction.
//   adj is ~50% zero -> alpha==0 contributes exact no-ops. Compact active j
//   per row (prefix-sum scan, no atomics, ascending order -> bit-identical
//   accumulation) and iterate only actives: main-loop VALU & LDS halve.
//   512 blocks x 1024 thr, 8 waves/SIMD, LDS ~49KB -> 2 blocks/CU.
__global__ __launch_bounds__(1024, 8) void mega_kernel(
    const float* __restrict__ base, const float* __restrict__ s1,
    const float* __restrict__ s2, const int* __restrict__ adj,
    const float* __restrict__ pd, const float* __restrict__ ut,
    const float* __restrict__ wpd, const float* __restrict__ wut,
    const float* __restrict__ W2t, const float* __restrict__ b2,
    float* __restrict__ out) {
    __shared__ float al[MROWS][N];         // 8KB alpha
    __shared__ float pdl[MROWS][N];        // 8KB staged pd rows
    __shared__ float utl[MROWS][N];        // 8KB staged ut rows
    __shared__ int   jlist[MROWS][N];      // 8KB active j indices (ascending)
    __shared__ float racc[16][MROWS][D];   // 16KB wave partials
    __shared__ float red[16], red2[16], gsum[MROWS];
    __shared__ int   wsum[16], gcnt[MROWS];
    __shared__ float tl[MROWS][D];         // 1KB

    const int tid = threadIdx.x;           // 0..1023
    const int i0 = blockIdx.x * MROWS;
    const float* pdb = pd + (size_t)i0 * N;
    const float* utb = ut + (size_t)i0 * N;

    // ---- stage pd/ut rows into LDS (coalesced float4) ----
    {
        int half = tid >> 9, idx = tid & 511;    // 512 float4 = 2 rows x 1024
        const float* src = half ? utb : pdb;
        float* dst = half ? &utl[0][0] : &pdl[0][0];
        ((float4*)dst)[idx] = ((const float4*)src)[idx];
    }

    // ---- phase 0: alpha + active-j compaction (row r <-> waves 8r..8r+7) ----
    {
        int r = tid >> 9;
        int i = i0 + r;
        int jb = (tid & 511) * 2;
        float s1i = s1[i];
        float2 sa = *(const float2*)&s2[jb];
        int2 ma = *(const int2*)&adj[i * N + jb];
        float e[2]; int mm[2];
        e[0] = s1i + sa.x; e[1] = s1i + sa.y;
        mm[0] = ma.x; mm[1] = ma.y;
        float mx = -3e38f;
        #pragma unroll
        for (int q = 0; q < 2; q++) {
            e[q] = e[q] > 0.f ? e[q] : LEAK * e[q];
            if (mm[q] > 0) mx = fmaxf(mx, e[q]);
        }
        #pragma unroll
        for (int off = 32; off > 0; off >>= 1) mx = fmaxf(mx, __shfl_xor(mx, off));
        int wid = tid >> 6, lane = tid & 63;
        // in-wave inclusive scan of active count (thread order = ascending j)
        int cl = (mm[0] > 0) + (mm[1] > 0);
        int incl = cl;
        #pragma unroll
        for (int s = 1; s < 64; s <<= 1) {
            int p = __shfl_up(incl, s);
            if (lane >= s) incl += p;
        }
        if (lane == 0) red[wid] = mx;
        if (lane == 63) wsum[wid] = incl;
        __syncthreads();
        {
            float m0 = fmaxf(fmaxf(red[8 * r], red[8 * r + 1]),
                             fmaxf(red[8 * r + 2], red[8 * r + 3]));
            float m1 = fmaxf(fmaxf(red[8 * r + 4], red[8 * r + 5]),
                             fmaxf(red[8 * r + 6], red[8 * r + 7]));
            mx = fmaxf(m0, m1);
        }
        // wave-base offsets + row total from wsum (visible after barrier #1)
        int base_off = 0, row_total = 0;
        #pragma unroll
        for (int w = 0; w < 8; w++) {
            int v = wsum[8 * r + w];
            if (8 * r + w < wid) base_off += v;
            row_total += v;
        }
        int off = base_off + incl - cl;          // exclusive offset for this thread
        if (mm[0] > 0) jlist[r][off] = jb;
        if (mm[1] > 0) jlist[r][off + (mm[0] > 0)] = jb + 1;
        if ((tid & 511) == 0) gcnt[r] = row_total;
        float ev[2]; float sum = 0.f;
        #pragma unroll
        for (int q = 0; q < 2; q++) {
            ev[q] = (mm[q] > 0) ? __expf(e[q] - mx) : 0.f;
            sum += ev[q];
        }
        #pragma unroll
        for (int off2 = 32; off2 > 0; off2 >>= 1) sum += __shfl_xor(sum, off2);
        if (lane == 0) red2[wid] = sum;
        __syncthreads();
        sum = red2[8 * r] + red2[8 * r + 1] + red2[8 * r + 2] + red2[8 * r + 3]
            + red2[8 * r + 4] + red2[8 * r + 5] + red2[8 * r + 6] + red2[8 * r + 7];
        float inv = sum > 0.f ? 1.f / sum : 0.f;
        *(float2*)&al[r][jb] = make_float2(ev[0] * inv, ev[1] * inv);
        if ((tid & 511) == 0) gsum[r] = sum;
    }
    __syncthreads();   // al/gsum/jlist/gcnt/pdl/utl visible; no barriers until epilogue

    const int l16 = tid & 15, g = tid >> 4;        // 64 groups x 16 lanes
    const int k0a = l16 * 4, k0b = 64 + l16 * 4;
    const float4 wp0 = *(const float4*)&wpd[k0a];
    const float4 wp1 = *(const float4*)&wpd[k0b];
    const float4 wu0 = *(const float4*)&wut[k0a];
    const float4 wu1 = *(const float4*)&wut[k0b];

    float4 a0[MROWS] = {}, a1[MROWS] = {};
    const int gc0 = gcnt[0], gc1 = gcnt[1];

    // ---- row 0: iterate active j only ----
    {
        int nc = (gc0 + 63) >> 6;
        #pragma unroll 2
        for (int c = 0; c < nc; c++) {
            int idx = c * 64 + g;
            if (idx < gc0) {
                int j = jlist[0][idx];
                float4 b0  = *(const float4*)&base[j * D + k0a];
                float4 b1v = *(const float4*)&base[j * D + k0b];
                float spd = pdl[0][j], sut = utl[0][j], sal = al[0][j];
                float v;
                v = fmaxf(fmaf(spd, wp0.x, fmaf(sut, wu0.x, b0.x)), 0.f);  a0[0].x = fmaf(sal, v, a0[0].x);
                v = fmaxf(fmaf(spd, wp0.y, fmaf(sut, wu0.y, b0.y)), 0.f);  a0[0].y = fmaf(sal, v, a0[0].y);
                v = fmaxf(fmaf(spd, wp0.z, fmaf(sut, wu0.z, b0.z)), 0.f);  a0[0].z = fmaf(sal, v, a0[0].z);
                v = fmaxf(fmaf(spd, wp0.w, fmaf(sut, wu0.w, b0.w)), 0.f);  a0[0].w = fmaf(sal, v, a0[0].w);
                v = fmaxf(fmaf(spd, wp1.x, fmaf(sut, wu1.x, b1v.x)), 0.f); a1[0].x = fmaf(sal, v, a1[0].x);
                v = fmaxf(fmaf(spd, wp1.y, fmaf(sut, wu1.y, b1v.y)), 0.f); a1[0].y = fmaf(sal, v, a1[0].y);
                v = fmaxf(fmaf(spd, wp1.z, fmaf(sut, wu1.z, b1v.z)), 0.f); a1[0].z = fmaf(sal, v, a1[0].z);
                v = fmaxf(fmaf(spd, wp1.w, fmaf(sut, wu1.w, b1v.w)), 0.f); a1[0].w = fmaf(sal, v, a1[0].w);
            }
        }
    }
    // ---- row 1 ----
    {
        int nc = (gc1 + 63) >> 6;
        #pragma unroll 2
        for (int c = 0; c < nc; c++) {
            int idx = c * 64 + g;
            if (idx < gc1) {
                int j = jlist[1][idx];
                float4 b0  = *(const float4*)&base[j * D + k0a];
                float4 b1v = *(const float4*)&base[j * D + k0b];
                float spd = pdl[1][j], sut = utl[1][j], sal = al[1][j];
                float v;
                v = fmaxf(fmaf(spd, wp0.x, fmaf(sut, wu0.x, b0.x)), 0.f);  a0[1].x = fmaf(sal, v, a0[1].x);
                v = fmaxf(fmaf(spd, wp0.y, fmaf(sut, wu0.y, b0.y)), 0.f);  a0[1].y = fmaf(sal, v, a0[1].y);
                v = fmaxf(fmaf(spd, wp0.z, fmaf(sut, wu0.z, b0.z)), 0.f);  a0[1].z = fmaf(sal, v, a0[1].z);
                v = fmaxf(fmaf(spd, wp0.w, fmaf(sut, wu0.w, b0.w)), 0.f);  a0[1].w = fmaf(sal, v, a0[1].w);
                v = fmaxf(fmaf(spd, wp1.x, fmaf(sut, wu1.x, b1v.x)), 0.f); a1[1].x = fmaf(sal, v, a1[1].x);
                v = fmaxf(fmaf(spd, wp1.y, fmaf(sut, wu1.y, b1v.y)), 0.f); a1[1].y = fmaf(sal, v, a1[1].y);
                v = fmaxf(fmaf(spd, wp1.z, fmaf(sut, wu1.z, b1v.z)), 0.f); a1[1].z = fmaf(sal, v, a1[1].z);
                v = fmaxf(fmaf(spd, wp1.w, fmaf(sut, wu1.w, b1v.w)), 0.f); a1[1].w = fmaf(sal, v, a1[1].w);
            }
        }
    }

    // ---- in-wave cross-group reduce: lanes l, l^16, l^32, l^48 share l16 ----
    #pragma unroll
    for (int r = 0; r < MROWS; r++) {
        #pragma unroll
        for (int m = 16; m <= 32; m <<= 1) {
            a0[r].x += __shfl_xor(a0[r].x, m); a0[r].y += __shfl_xor(a0[r].y, m);
            a0[r].z += __shfl_xor(a0[r].z, m); a0[r].w += __shfl_xor(a0[r].w, m);
            a1[r].x += __shfl_xor(a1[r].x, m); a1[r].y += __shfl_xor(a1[r].y, m);
            a1[r].z += __shfl_xor(a1[r].z, m); a1[r].w += __shfl_xor(a1[r].w, m);
        }
    }
    {
        int w = tid >> 6, lane = tid & 63;
        if (lane < 16) {
            #pragma unroll
            for (int r = 0; r < MROWS; r++) {
                *(float4*)&racc[w][r][k0a] = a0[r];
                *(float4*)&racc[w][r][k0b] = a1[r];
            }
        }
    }
    __syncthreads();
    if (tid < 256) {
        int rr = tid >> 7, k = tid & 127;
        float v = 0.f;
        #pragma unroll
        for (int w = 0; w < 16; w++) v += racc[w][rr][k];
        tl[rr][k] = v;
    }
    __syncthreads();
    // ---- final GEMM: out[i][d] = sum_k t[k] * W2t[k][d] + gate*b2[d] ----
    if (tid < 256) {
        int rr = tid >> 7, d = tid & 127;
        float acc = (gsum[rr] > 0.f) ? b2[d] : 0.f;
        #pragma unroll 8
        for (int k = 0; k < D; k++)
            acc = fmaf(tl[rr][k], W2t[k * D + d], acc);
        out[(i0 + rr) * D + d] = acc;
    }
}

// ---------------------------------------------------------------------------
extern "C" void kernel_launch(void* const* d_in, const int* in_sizes, int n_in,
                              void* d_out, int out_size, void* d_ws, size_t ws_size,
                              hipStream_t stream) {
    (void)in_sizes; (void)n_in; (void)out_size; (void)ws_size;
    const float* h   = (const float*)d_in[0];
    const int*   adj = (const int*)d_in[1];
    const float* pd  = (const float*)d_in[2];
    const float* ut  = (const float*)d_in[3];
    const float* W   = (const float*)d_in[4];
    const float* a   = (const float*)d_in[5];
    const float* W1  = (const float*)d_in[6];
    const float* b1  = (const float*)d_in[7];
    const float* W2  = (const float*)d_in[8];
    const float* b2  = (const float*)d_in[9];
    float* out = (float*)d_out;
    float* ws = (float*)d_ws;

    float* W2t   = ws + OFF_W2T;
    float* wpd   = ws + OFF_WPD;
    float* wut   = ws + OFF_WUT;
    float* s1    = ws + OFF_S1;
    float* s2    = ws + OFF_S2;
    float* baseb = ws + OFF_BASE;

    prep_base_kernel<<<517, 256, 0, stream>>>(W, W1, W2, a, h, b1,
                                              W2t, wpd, wut, s1, s2, baseb);
    mega_kernel<<<N / MROWS, 1024, 0, stream>>>(baseb, s1, s2, adj, pd, ut,
                                                wpd, wut, W2t, b2, out);
}

// Round 21
// 36.921 us; speedup vs baseline: 1.1133x; 1.0092x over previous
//
#include <hip/hip_runtime.h>
#include <hip/hip_bf16.h>

#define N 1024
#define D 128
#define LEAK 0.2f

#define MROWS 2          // i-rows per mega block

// workspace layout (float offsets)
#define OFF_W2T  0
#define OFF_WPD  16384
#define OFF_WUT  16512
#define OFF_S1   16640
#define OFF_S2   17664
#define OFF_BASE 18688

// ---------------------------------------------------------------------------
// K_A: prep + base, v3 (byte-identical to rounds 14/17/20 — known-good).
__global__ __launch_bounds__(256) void prep_base_kernel(
    const float* __restrict__ W, const float* __restrict__ W1,
    const float* __restrict__ W2, const float* __restrict__ a,
    const float* __restrict__ h, const float* __restrict__ b1,
    float* __restrict__ W2t, float* __restrict__ wpd, float* __restrict__ wut,
    float* __restrict__ s1, float* __restrict__ s2, float* __restrict__ base) {
    __shared__ float pool[4160];
    __shared__ float red[4], red2[4];
    int b = blockIdx.x, tid = threadIdx.x;
    if (b < 512) {
        float* hl  = pool;          // [2][128]
        float* whl = pool + 256;    // [2][128]
        int i0 = b * 2;
        if (tid < 64) ((float4*)hl)[tid] = ((const float4*)(h + i0 * D))[tid];
        __syncthreads();
        int r = tid >> 7, l = tid & 127;
        float u = 0.f;
        #pragma unroll 8
        for (int q = 0; q < D; q += 4) {
            float4 hq = *(const float4*)&hl[r * D + q];
            float4 wq = *(const float4*)&W[l * D + q];
            u = fmaf(hq.x, wq.x, u); u = fmaf(hq.y, wq.y, u);
            u = fmaf(hq.z, wq.z, u); u = fmaf(hq.w, wq.w, u);
        }
        whl[r * D + l] = u;
        __syncthreads();
        {
            int w = tid >> 6, l63 = tid & 63;
            int row = w >> 1, half = w & 1;
            float wh = whl[row * D + half * 64 + l63];
            float p1 = wh * a[half * 64 + l63];
            float p2 = wh * a[D + half * 64 + l63];
            #pragma unroll
            for (int off = 32; off > 0; off >>= 1) {
                p1 += __shfl_xor(p1, off);
                p2 += __shfl_xor(p2, off);
            }
            if (l63 == 0) { red[w] = p1; red2[w] = p2; }
        }
        __syncthreads();
        if (tid < 2) {
            s1[i0 + tid] = red[2 * tid] + red[2 * tid + 1];
            s2[i0 + tid] = red2[2 * tid] + red2[2 * tid + 1];
        }
        float acc = b1[l];
        #pragma unroll 8
        for (int q = 0; q < D; q += 2) {
            float2 wh2 = *(const float2*)&whl[r * D + q];
            float2 x = *(const float2*)&W1[l * (D + 2) + q];
            acc = fmaf(wh2.x, x.x, acc);
            acc = fmaf(wh2.y, x.y, acc);
        }
        base[(i0 + r) * D + l] = acc;
    } else if (b < 516) {
        int kbase = 32 * (b - 512);
        #pragma unroll
        for (int p = 0; p < 16; p++) {
            int idx = tid + p * 256;
            int rd = idx >> 5, cc = idx & 31;
            pool[cc * 129 + rd] = W2[rd * D + kbase + cc];
        }
        __syncthreads();
        #pragma unroll
        for (int p = 0; p < 16; p++) {
            int idx = tid + p * 256;
            int kl = idx >> 7, dd = idx & 127;
            W2t[(kbase + kl) * D + dd] = pool[kl * 129 + dd];
        }
    } else {
        if (tid < 128) wpd[tid] = W1[tid * (D + 2) + D];
        else           wut[tid - 128] = W1[(tid - 128) * (D + 2) + D + 1];
    }
}

// ---------------------------------------------------------------------------
// K_B: mega v14 = v13 (R20, 37.3us) with compacted payload packed into one
//   float4: scc[r][idx] = {pd, ut, alpha, j-as-bits}. Main loop per active j:
//   1 LDS b128 broadcast + 2 global b128 (was 4 LDS instr + 2 global).
//   Same iteration order as v13 -> bit-identical accumulation.
//   512 blocks x 1024 thr, 8 waves/SIMD, LDS ~50KB -> 2 blocks/CU.
__global__ __launch_bounds__(1024, 8) void mega_kernel(
    const float* __restrict__ base, const float* __restrict__ s1,
    const float* __restrict__ s2, const int* __restrict__ adj,
    const float* __restrict__ pd, const float* __restrict__ ut,
    const float* __restrict__ wpd, const float* __restrict__ wut,
    const float* __restrict__ W2t, const float* __restrict__ b2,
    float* __restrict__ out) {
    __shared__ float4 scc[MROWS][N];       // 32KB compacted {pd, ut, alpha, jbits}
    __shared__ float racc[16][MROWS][D];   // 16KB wave partials
    __shared__ float red[16], red2[16], gsum[MROWS];
    __shared__ int   wsum[16], gcnt[MROWS];
    __shared__ float tl[MROWS][D];         // 1KB

    const int tid = threadIdx.x;           // 0..1023
    const int i0 = blockIdx.x * MROWS;
    const float* pdb = pd + (size_t)i0 * N;
    const float* utb = ut + (size_t)i0 * N;

    // ---- phase 0: alpha + compaction (row r <-> waves 8r..8r+7) ----
    {
        int r = tid >> 9;
        int i = i0 + r;
        int jb = (tid & 511) * 2;
        float s1i = s1[i];
        float2 sa = *(const float2*)&s2[jb];
        int2 ma = *(const int2*)&adj[i * N + jb];
        float2 pdv = *(const float2*)&pdb[r * N + jb];   // coalesced float2
        float2 utv = *(const float2*)&utb[r * N + jb];
        float e[2]; int mm[2];
        e[0] = s1i + sa.x; e[1] = s1i + sa.y;
        mm[0] = ma.x; mm[1] = ma.y;
        float mx = -3e38f;
        #pragma unroll
        for (int q = 0; q < 2; q++) {
            e[q] = e[q] > 0.f ? e[q] : LEAK * e[q];
            if (mm[q] > 0) mx = fmaxf(mx, e[q]);
        }
        #pragma unroll
        for (int off = 32; off > 0; off >>= 1) mx = fmaxf(mx, __shfl_xor(mx, off));
        int wid = tid >> 6, lane = tid & 63;
        // in-wave inclusive scan of active count (thread order = ascending j)
        int cl = (mm[0] > 0) + (mm[1] > 0);
        int incl = cl;
        #pragma unroll
        for (int s = 1; s < 64; s <<= 1) {
            int p = __shfl_up(incl, s);
            if (lane >= s) incl += p;
        }
        if (lane == 0) red[wid] = mx;
        if (lane == 63) wsum[wid] = incl;
        __syncthreads();
        {
            float m0 = fmaxf(fmaxf(red[8 * r], red[8 * r + 1]),
                             fmaxf(red[8 * r + 2], red[8 * r + 3]));
            float m1 = fmaxf(fmaxf(red[8 * r + 4], red[8 * r + 5]),
                             fmaxf(red[8 * r + 6], red[8 * r + 7]));
            mx = fmaxf(m0, m1);
        }
        int base_off = 0, row_total = 0;
        #pragma unroll
        for (int w = 0; w < 8; w++) {
            int v = wsum[8 * r + w];
            if (8 * r + w < wid) base_off += v;
            row_total += v;
        }
        int off = base_off + incl - cl;          // exclusive offset for this thread
        if ((tid & 511) == 0) gcnt[r] = row_total;
        float ev[2]; float sum = 0.f;
        #pragma unroll
        for (int q = 0; q < 2; q++) {
            ev[q] = (mm[q] > 0) ? __expf(e[q] - mx) : 0.f;
            sum += ev[q];
        }
        #pragma unroll
        for (int off2 = 32; off2 > 0; off2 >>= 1) sum += __shfl_xor(sum, off2);
        if (lane == 0) red2[wid] = sum;
        __syncthreads();
        sum = red2[8 * r] + red2[8 * r + 1] + red2[8 * r + 2] + red2[8 * r + 3]
            + red2[8 * r + 4] + red2[8 * r + 5] + red2[8 * r + 6] + red2[8 * r + 7];
        float inv = sum > 0.f ? 1.f / sum : 0.f;
        if (mm[0] > 0)
            scc[r][off] = make_float4(pdv.x, utv.x, ev[0] * inv, __int_as_float(jb));
        if (mm[1] > 0)
            scc[r][off + (mm[0] > 0)] = make_float4(pdv.y, utv.y, ev[1] * inv,
                                                    __int_as_float(jb + 1));
        if ((tid & 511) == 0) gsum[r] = sum;
    }
    __syncthreads();   // scc/gcnt/gsum visible; no barriers until epilogue

    const int l16 = tid & 15, g = tid >> 4;        // 64 groups x 16 lanes
    const int k0a = l16 * 4, k0b = 64 + l16 * 4;
    const float4 wp0 = *(const float4*)&wpd[k0a];
    const float4 wp1 = *(const float4*)&wpd[k0b];
    const float4 wu0 = *(const float4*)&wut[k0a];
    const float4 wu1 = *(const float4*)&wut[k0b];

    float4 a0[MROWS] = {}, a1[MROWS] = {};
    const int gc0 = gcnt[0], gc1 = gcnt[1];

    // ---- row 0: iterate active j only (1 LDS b128 + 2 global b128 each) ----
    {
        int nc = (gc0 + 63) >> 6;
        #pragma unroll 2
        for (int c = 0; c < nc; c++) {
            int idx = c * 64 + g;
            if (idx < gc0) {
                float4 s = scc[0][idx];
                int j = __float_as_int(s.w);
                float4 b0  = *(const float4*)&base[j * D + k0a];
                float4 b1v = *(const float4*)&base[j * D + k0b];
                float v;
                v = fmaxf(fmaf(s.x, wp0.x, fmaf(s.y, wu0.x, b0.x)), 0.f);  a0[0].x = fmaf(s.z, v, a0[0].x);
                v = fmaxf(fmaf(s.x, wp0.y, fmaf(s.y, wu0.y, b0.y)), 0.f);  a0[0].y = fmaf(s.z, v, a0[0].y);
                v = fmaxf(fmaf(s.x, wp0.z, fmaf(s.y, wu0.z, b0.z)), 0.f);  a0[0].z = fmaf(s.z, v, a0[0].z);
                v = fmaxf(fmaf(s.x, wp0.w, fmaf(s.y, wu0.w, b0.w)), 0.f);  a0[0].w = fmaf(s.z, v, a0[0].w);
                v = fmaxf(fmaf(s.x, wp1.x, fmaf(s.y, wu1.x, b1v.x)), 0.f); a1[0].x = fmaf(s.z, v, a1[0].x);
                v = fmaxf(fmaf(s.x, wp1.y, fmaf(s.y, wu1.y, b1v.y)), 0.f); a1[0].y = fmaf(s.z, v, a1[0].y);
                v = fmaxf(fmaf(s.x, wp1.z, fmaf(s.y, wu1.z, b1v.z)), 0.f); a1[0].z = fmaf(s.z, v, a1[0].z);
                v = fmaxf(fmaf(s.x, wp1.w, fmaf(s.y, wu1.w, b1v.w)), 0.f); a1[0].w = fmaf(s.z, v, a1[0].w);
            }
        }
    }
    // ---- row 1 ----
    {
        int nc = (gc1 + 63) >> 6;
        #pragma unroll 2
        for (int c = 0; c < nc; c++) {
            int idx = c * 64 + g;
            if (idx < gc1) {
                float4 s = scc[1][idx];
                int j = __float_as_int(s.w);
                float4 b0  = *(const float4*)&base[j * D + k0a];
                float4 b1v = *(const float4*)&base[j * D + k0b];
                float v;
                v = fmaxf(fmaf(s.x, wp0.x, fmaf(s.y, wu0.x, b0.x)), 0.f);  a0[1].x = fmaf(s.z, v, a0[1].x);
                v = fmaxf(fmaf(s.x, wp0.y, fmaf(s.y, wu0.y, b0.y)), 0.f);  a0[1].y = fmaf(s.z, v, a0[1].y);
                v = fmaxf(fmaf(s.x, wp0.z, fmaf(s.y, wu0.z, b0.z)), 0.f);  a0[1].z = fmaf(s.z, v, a0[1].z);
                v = fmaxf(fmaf(s.x, wp0.w, fmaf(s.y, wu0.w, b0.w)), 0.f);  a0[1].w = fmaf(s.z, v, a0[1].w);
                v = fmaxf(fmaf(s.x, wp1.x, fmaf(s.y, wu1.x, b1v.x)), 0.f); a1[1].x = fmaf(s.z, v, a1[1].x);
                v = fmaxf(fmaf(s.x, wp1.y, fmaf(s.y, wu1.y, b1v.y)), 0.f); a1[1].y = fmaf(s.z, v, a1[1].y);
                v = fmaxf(fmaf(s.x, wp1.z, fmaf(s.y, wu1.z, b1v.z)), 0.f); a1[1].z = fmaf(s.z, v, a1[1].z);
                v = fmaxf(fmaf(s.x, wp1.w, fmaf(s.y, wu1.w, b1v.w)), 0.f); a1[1].w = fmaf(s.z, v, a1[1].w);
            }
        }
    }

    // ---- in-wave cross-group reduce: lanes l, l^16, l^32, l^48 share l16 ----
    #pragma unroll
    for (int r = 0; r < MROWS; r++) {
        #pragma unroll
        for (int m = 16; m <= 32; m <<= 1) {
            a0[r].x += __shfl_xor(a0[r].x, m); a0[r].y += __shfl_xor(a0[r].y, m);
            a0[r].z += __shfl_xor(a0[r].z, m); a0[r].w += __shfl_xor(a0[r].w, m);
            a1[r].x += __shfl_xor(a1[r].x, m); a1[r].y += __shfl_xor(a1[r].y, m);
            a1[r].z += __shfl_xor(a1[r].z, m); a1[r].w += __shfl_xor(a1[r].w, m);
        }
    }
    {
        int w = tid >> 6, lane = tid & 63;
        if (lane < 16) {
            #pragma unroll
            for (int r = 0; r < MROWS; r++) {
                *(float4*)&racc[w][r][k0a] = a0[r];
                *(float4*)&racc[w][r][k0b] = a1[r];
            }
        }
    }
    __syncthreads();
    if (tid < 256) {
        int rr = tid >> 7, k = tid & 127;
        float v = 0.f;
        #pragma unroll
        for (int w = 0; w < 16; w++) v += racc[w][rr][k];
        tl[rr][k] = v;
    }
    __syncthreads();
    // ---- final GEMM: out[i][d] = sum_k t[k] * W2t[k][d] + gate*b2[d] ----
    if (tid < 256) {
        int rr = tid >> 7, d = tid & 127;
        float acc = (gsum[rr] > 0.f) ? b2[d] : 0.f;
        #pragma unroll 8
        for (int k = 0; k < D; k++)
            acc = fmaf(tl[rr][k], W2t[k * D + d], acc);
        out[(i0 + rr) * D + d] = acc;
    }
}

// ---------------------------------------------------------------------------
extern "C" void kernel_launch(void* const* d_in, const int* in_sizes, int n_in,
                              void* d_out, int out_size, void* d_ws, size_t ws_size,
                              hipStream_t stream) {
    (void)in_sizes; (void)n_in; (void)out_size; (void)ws_size;
    const float* h   = (const float*)d_in[0];
    const int*   adj = (const int*)d_in[1];
    const float* pd  = (const float*)d_in[2];
    const float* ut  = (const float*)d_in[3];
    const float* W   = (const float*)d_in[4];
    const float* a   = (const float*)d_in[5];
    const float* W1  = (const float*)d_in[6];
    const float* b1  = (const float*)d_in[7];
    const float* W2  = (const float*)d_in[8];
    const float* b2  = (const float*)d_in[9];
    float* out = (float*)d_out;
    float* ws = (float*)d_ws;

    float* W2t   = ws + OFF_W2T;
    float* wpd   = ws + OFF_WPD;
    float* wut   = ws + OFF_WUT;
    float* s1    = ws + OFF_S1;
    float* s2    = ws + OFF_S2;
    float* baseb = ws + OFF_BASE;

    prep_base_kernel<<<517, 256, 0, stream>>>(W, W1, W2, a, h, b1,
                                              W2t, wpd, wut, s1, s2, baseb);
    mega_kernel<<<N / MROWS, 1024, 0, stream>>>(baseb, s1, s2, adj, pd, ut,
                                                wpd, wut, W2t, b2, out);
}